// Round 7
// baseline (10259.730 us; speedup 1.0000x reference)
//
#include <hip/hip_runtime.h>
#include <stdint.h>

#define NN 4096
#define BB 4
#define RPB 16          // rows per block
#define TPB 1024

// ---------- bf16 round-to-nearest-even ----------
__device__ __forceinline__ uint32_t bf16rne(float f) {
  uint32_t u = __float_as_uint(f);
  return (u + 0x7FFFu + ((u >> 16) & 1u)) >> 16;
}

// ---------- straight pack: Bp[row*NN+c] = bf16(Br)|bf16(Bi)<<16 ----------
__global__ void pack_kernel(const float* __restrict__ Br, const float* __restrict__ Bi,
                            uint32_t* __restrict__ Bp) {
  int i = blockIdx.x * blockDim.x + threadIdx.x;   // over N*N/4
  float4 r = reinterpret_cast<const float4*>(Br)[i];
  float4 m = reinterpret_cast<const float4*>(Bi)[i];
  uint4 o;
  o.x = bf16rne(r.x) | (bf16rne(m.x) << 16);
  o.y = bf16rne(r.y) | (bf16rne(m.y) << 16);
  o.z = bf16rne(r.z) | (bf16rne(m.z) << 16);
  o.w = bf16rne(r.w) | (bf16rne(m.w) << 16);
  reinterpret_cast<uint4*>(Bp)[i] = o;
}

// ---------- x0 = exp(i*theta): state (complex interleaved) + out real plane t=0 ----------
__global__ void init_kernel(const float* __restrict__ ang,
                            float2* __restrict__ st0, float* __restrict__ out0) {
  int i = blockIdx.x * blockDim.x + threadIdx.x;
  if (i < BB * NN) {
    float s, c;
    sincosf(ang[i], &s, &c);
    st0[i] = make_float2(c, s);
    out0[i] = c;
  }
}

// ---------- one recurrence step ----------
// state [b][n] complex interleaved (float2); d_out gets REAL part only, [t][b][n]
// LDS x: logical float4 n={r0,i0,r1,i1} at physical p(n)=n^((n>>4)&3) (round-6 swizzle).
template <bool PACKED>
__global__ __launch_bounds__(TPB)
void step_kernel(const uint32_t* __restrict__ Bp,
                 const float* __restrict__ Brf,
                 const float* __restrict__ Bif,
                 const float* __restrict__ omega,
                 const float2* __restrict__ stPrev,
                 float2* __restrict__ stNext,
                 float* __restrict__ outRe) {
  extern __shared__ float lds[];
  float* xl  = lds;                // 4096 float4 = 64 KB (batches 0,1)
  float* xh  = lds + NN * 4;       // 64 KB (batches 2,3)
  float* red = lds + NN * 8;       // 2 KB

  const int tid = threadIdx.x;

  // ---- stage x_t into LDS: one swizzled b128 write per thread-iter ----
#pragma unroll
  for (int k = 0; k < 8; ++k) {
    int idx  = tid + k * TPB;            // 0..8191
    int half = idx >> 12;                // 0 -> xl, 1 -> xh
    int n    = idx & (NN - 1);
    float2 v0 = stPrev[(half * 2    ) * NN + n];
    float2 v1 = stPrev[(half * 2 + 1) * NN + n];
    float4 w4 = make_float4(v0.x, v0.y, v1.x, v1.y);
    int p = n ^ ((n >> 4) & 3);          // swizzled physical slot
    reinterpret_cast<float4*>(half ? xh : xl)[p] = w4;
  }
  __syncthreads();

  const int w    = tid >> 6;
  const int lane = tid & 63;
  const int rg   = w >> 2;             // row group (4 rows)
  const int q    = w & 3;              // n-quarter
  const int row0 = blockIdx.x * RPB + rg * 4;
  const int xk   = (lane >> 2) & 3;    // swizzle key for this lane's 4-float4 window

  float acc[32];
#pragma unroll
  for (int i = 0; i < 32; ++i) acc[i] = 0.0f;

// BASE is a compile-time literal (0/8/16/24) after unroll -> all acc indices static.
#define CFMA(BASE, BR, BI, XA, XB)                                              \
  acc[BASE+0] = fmaf(BR, XA.x, acc[BASE+0]); acc[BASE+0] = fmaf(-BI, XA.y, acc[BASE+0]); \
  acc[BASE+1] = fmaf(BR, XA.y, acc[BASE+1]); acc[BASE+1] = fmaf(BI, XA.x, acc[BASE+1]);  \
  acc[BASE+2] = fmaf(BR, XA.z, acc[BASE+2]); acc[BASE+2] = fmaf(-BI, XA.w, acc[BASE+2]); \
  acc[BASE+3] = fmaf(BR, XA.w, acc[BASE+3]); acc[BASE+3] = fmaf(BI, XA.z, acc[BASE+3]);  \
  acc[BASE+4] = fmaf(BR, XB.x, acc[BASE+4]); acc[BASE+4] = fmaf(-BI, XB.y, acc[BASE+4]); \
  acc[BASE+5] = fmaf(BR, XB.y, acc[BASE+5]); acc[BASE+5] = fmaf(BI, XB.x, acc[BASE+5]);  \
  acc[BASE+6] = fmaf(BR, XB.z, acc[BASE+6]); acc[BASE+6] = fmaf(-BI, XB.w, acc[BASE+6]); \
  acc[BASE+7] = fmaf(BR, XB.w, acc[BASE+7]); acc[BASE+7] = fmaf(BI, XB.z, acc[BASE+7]);

#define CROW(RLIT)                                                              \
  {                                                                             \
    uint4 pv = pr[RLIT][i4 * 64 + lane];                                        \
    uint32_t u;                                                                 \
    u = pv.x; { float br = __uint_as_float(u << 16), bi = __uint_as_float(u & 0xFFFF0000u); CFMA(RLIT*8, br, bi, xa[0], xb[0]) } \
    u = pv.y; { float br = __uint_as_float(u << 16), bi = __uint_as_float(u & 0xFFFF0000u); CFMA(RLIT*8, br, bi, xa[1], xb[1]) } \
    u = pv.z; { float br = __uint_as_float(u << 16), bi = __uint_as_float(u & 0xFFFF0000u); CFMA(RLIT*8, br, bi, xa[2], xb[2]) } \
    u = pv.w; { float br = __uint_as_float(u << 16), bi = __uint_as_float(u & 0xFFFF0000u); CFMA(RLIT*8, br, bi, xa[3], xb[3]) } \
  }

  if (PACKED) {
    const uint4* pr[4];
#pragma unroll
    for (int r = 0; r < 4; ++r)
      pr[r] = reinterpret_cast<const uint4*>(Bp + (size_t)(row0 + r) * NN + q * 1024);
#pragma unroll
    for (int i4 = 0; i4 < 4; ++i4) {
      const int n0 = q * 1024 + i4 * 256 + lane * 4;   // logical float4 idx
      float4 xa[4], xb[4];
#pragma unroll
      for (int j = 0; j < 4; ++j) {
        int p = n0 + (j ^ xk);           // physical slot of logical column n0+j
        xa[j] = reinterpret_cast<const float4*>(xl)[p];
        xb[j] = reinterpret_cast<const float4*>(xh)[p];
      }
      CROW(0) CROW(1) CROW(2) CROW(3)
    }
  } else {
    const float4* rr[4];
    const float4* ir[4];
#pragma unroll
    for (int r = 0; r < 4; ++r) {
      rr[r] = reinterpret_cast<const float4*>(Brf + (size_t)(row0 + r) * NN + q * 1024);
      ir[r] = reinterpret_cast<const float4*>(Bif + (size_t)(row0 + r) * NN + q * 1024);
    }
#define FROW(RLIT)                                                              \
    {                                                                           \
      float4 pvr = rr[RLIT][i4 * 64 + lane];                                    \
      float4 pvi = ir[RLIT][i4 * 64 + lane];                                    \
      CFMA(RLIT*8, pvr.x, pvi.x, xa[0], xb[0])                                  \
      CFMA(RLIT*8, pvr.y, pvi.y, xa[1], xb[1])                                  \
      CFMA(RLIT*8, pvr.z, pvi.z, xa[2], xb[2])                                  \
      CFMA(RLIT*8, pvr.w, pvi.w, xa[3], xb[3])                                  \
    }
#pragma unroll
    for (int i4 = 0; i4 < 4; ++i4) {
      const int n0 = q * 1024 + i4 * 256 + lane * 4;
      float4 xa[4], xb[4];
#pragma unroll
      for (int j = 0; j < 4; ++j) {
        int p = n0 + (j ^ xk);
        xa[j] = reinterpret_cast<const float4*>(xl)[p];
        xb[j] = reinterpret_cast<const float4*>(xh)[p];
      }
      FROW(0) FROW(1) FROW(2) FROW(3)
    }
#undef FROW
  }
#undef CROW
#undef CFMA

  // ---- halving butterfly: 32 values over 64 lanes in 32 shfls (was 192) ----
  // After level (mask m): lower lanes keep sums of value-indices [0..half),
  // upper lanes keep [half..2*half). Final: lane pair 2t,2t+1 holds sum of
  // value j=(lane>>1)&31; even lane writes red[w][j].
#pragma unroll
  for (int k = 0; k < 5; ++k) {
    const int m    = 32 >> k;
    const int half = 16 >> k;
    const bool up  = (lane & m) != 0;
#pragma unroll
    for (int i = 0; i < half; ++i) {
      float send = up ? acc[i] : acc[i + half];
      float got  = __shfl_xor(send, m, 64);
      acc[i] = (up ? acc[i + half] : acc[i]) + got;
    }
  }
  {
    float vfin = acc[0] + __shfl_xor(acc[0], 1, 64);
    if (!(lane & 1)) red[w * 32 + ((lane >> 1) & 31)] = vfin;
  }
  __syncthreads();

  // ---- cross-wave sum + diagonal term + writes ----
  if (tid < 128) {
    int rg2 = tid >> 5;
    int v   = tid & 31;
    float s = red[(rg2 * 4 + 0) * 32 + v] + red[(rg2 * 4 + 1) * 32 + v] +
              red[(rg2 * 4 + 2) * 32 + v] + red[(rg2 * 4 + 3) * 32 + v];
    int r  = v >> 3;
    int c  = v & 7;
    int b  = c >> 1;
    int ri = c & 1;
    int m  = blockIdx.x * RPB + rg2 * 4 + r;
    float om = omega[b * NN + m];
    const float* xs = (b < 2) ? xl : xh;
    int mp = m ^ ((m >> 4) & 3);         // swizzled physical slot of node m
    float xr = xs[mp * 4 + (b & 1) * 2];
    float xi = xs[mp * 4 + (b & 1) * 2 + 1];
    // i*omega*(xr + i*xi) = -omega*xi + i*omega*xr
    s += (ri == 0) ? (-om * xi) : (om * xr);
    reinterpret_cast<float*>(stNext)[(b * NN + m) * 2 + ri] = s;
    if (ri == 0) outRe[b * NN + m] = s;  // d_out = REAL part only, [t][b][n]
  }
}

// ---------- host ----------
extern "C" void kernel_launch(void* const* d_in, const int* in_sizes, int n_in,
                              void* d_out, int out_size, void* d_ws, size_t ws_size,
                              hipStream_t stream) {
  const float* B_real = (const float*)d_in[0];
  const float* B_imag = (const float*)d_in[1];
  const float* omega  = (const float*)d_in[2];
  const float* ang    = (const float*)d_in[3];
  float* out = (float*)d_out;

  const int NT = out_size / (BB * NN);                           // 256
  const size_t packBytes = (size_t)NN * NN * sizeof(uint32_t);   // 67 MB
  const size_t stBytes   = (size_t)2 * BB * NN * sizeof(float2); // 256 KB
  const bool packed = ws_size >= packBytes + stBytes;

  uint32_t* Bp;
  float2* st;
  if (packed) {
    Bp = (uint32_t*)d_ws;
    st = (float2*)((char*)d_ws + packBytes);
  } else {
    Bp = nullptr;
    st = (float2*)d_ws;                                          // needs 256 KB
  }
  float2* st0 = st;
  float2* st1 = st + BB * NN;

  const size_t shmem = (size_t)(NN * 8 + 16 * 32) * sizeof(float);  // 133120 B
  (void)hipFuncSetAttribute((const void*)&step_kernel<true>,
                            hipFuncAttributeMaxDynamicSharedMemorySize, (int)shmem);
  (void)hipFuncSetAttribute((const void*)&step_kernel<false>,
                            hipFuncAttributeMaxDynamicSharedMemorySize, (int)shmem);

  if (packed) {
    pack_kernel<<<NN * NN / 4 / 256, 256, 0, stream>>>(B_real, B_imag, Bp);
  }
  init_kernel<<<(BB * NN + 255) / 256, 256, 0, stream>>>(ang, st0, out);

  for (int t = 1; t < NT; ++t) {
    float2* sp = ((t - 1) & 1) ? st1 : st0;
    float2* sn = (t & 1) ? st1 : st0;
    float* outT = out + (size_t)t * BB * NN;
    if (packed) {
      step_kernel<true><<<NN / RPB, TPB, shmem, stream>>>(
          Bp, nullptr, nullptr, omega, sp, sn, outT);
    } else {
      step_kernel<false><<<NN / RPB, TPB, shmem, stream>>>(
          nullptr, B_real, B_imag, omega, sp, sn, outT);
    }
  }
}

// Round 8
// 3941.731 us; speedup vs baseline: 2.6028x; 2.6028x over previous
//
#include <hip/hip_runtime.h>
#include <stdint.h>

#define NN 4096
#define BB 4
#define RPB 16          // rows per block
#define TPB 1024

// ---------- bf16 round-to-nearest-even ----------
__device__ __forceinline__ uint32_t bf16rne(float f) {
  uint32_t u = __float_as_uint(f);
  return (u + 0x7FFFu + ((u >> 16) & 1u)) >> 16;
}

// ---------- straight pack: Bp[row*NN+c] = bf16(Br)|bf16(Bi)<<16 ----------
__global__ void pack_kernel(const float* __restrict__ Br, const float* __restrict__ Bi,
                            uint32_t* __restrict__ Bp) {
  int i = blockIdx.x * blockDim.x + threadIdx.x;   // over N*N/4
  float4 r = reinterpret_cast<const float4*>(Br)[i];
  float4 m = reinterpret_cast<const float4*>(Bi)[i];
  uint4 o;
  o.x = bf16rne(r.x) | (bf16rne(m.x) << 16);
  o.y = bf16rne(r.y) | (bf16rne(m.y) << 16);
  o.z = bf16rne(r.z) | (bf16rne(m.z) << 16);
  o.w = bf16rne(r.w) | (bf16rne(m.w) << 16);
  reinterpret_cast<uint4*>(Bp)[i] = o;
}

// ---------- x0 = exp(i*theta): state (complex interleaved) + out real plane t=0 ----------
__global__ void init_kernel(const float* __restrict__ ang,
                            float2* __restrict__ st0, float* __restrict__ out0) {
  int i = blockIdx.x * blockDim.x + threadIdx.x;
  if (i < BB * NN) {
    float s, c;
    sincosf(ang[i], &s, &c);
    st0[i] = make_float2(c, s);
    out0[i] = c;
  }
}

// ---------- one recurrence step ----------
// state [b][n] complex interleaved (float2); d_out gets REAL part only, [t][b][n]
// LDS x: logical float4 n={r0,i0,r1,i1} at physical p(n)=n^((n>>4)&3).
template <bool PACKED>
__global__ __launch_bounds__(TPB)
void step_kernel(const uint32_t* __restrict__ Bp,
                 const float* __restrict__ Brf,
                 const float* __restrict__ Bif,
                 const float* __restrict__ omega,
                 const float2* __restrict__ stPrev,
                 float2* __restrict__ stNext,
                 float* __restrict__ outRe) {
  extern __shared__ float lds[];
  float* xl  = lds;                // 4096 float4 = 64 KB (batches 0,1)
  float* xh  = lds + NN * 4;       // 64 KB (batches 2,3)
  float* red = lds + NN * 8;       // 2 KB

  const int tid = threadIdx.x;

  // ---- stage x_t into LDS: one swizzled b128 write per thread-iter ----
#pragma unroll
  for (int k = 0; k < 8; ++k) {
    int idx  = tid + k * TPB;            // 0..8191
    int half = idx >> 12;                // 0 -> xl, 1 -> xh
    int n    = idx & (NN - 1);
    float2 v0 = stPrev[(half * 2    ) * NN + n];
    float2 v1 = stPrev[(half * 2 + 1) * NN + n];
    float4 w4 = make_float4(v0.x, v0.y, v1.x, v1.y);
    int p = n ^ ((n >> 4) & 3);          // swizzled physical slot
    reinterpret_cast<float4*>(half ? xh : xl)[p] = w4;
  }
  __syncthreads();

  const int w    = tid >> 6;
  const int lane = tid & 63;
  const int rg   = w >> 2;             // row group (4 rows)
  const int q    = w & 3;              // n-quarter
  const int row0 = blockIdx.x * RPB + rg * 4;
  const int xk   = (lane >> 2) & 3;    // swizzle key for this lane's 4-float4 window

  float acc[4][8];
#pragma unroll
  for (int r = 0; r < 4; ++r)
#pragma unroll
    for (int c = 0; c < 8; ++c) acc[r][c] = 0.0f;

#define CFMA(A, BR, BI, XA, XB)                                   \
  A[0] = fmaf(BR, XA.x, A[0]); A[0] = fmaf(-BI, XA.y, A[0]);      \
  A[1] = fmaf(BR, XA.y, A[1]); A[1] = fmaf(BI, XA.x, A[1]);       \
  A[2] = fmaf(BR, XA.z, A[2]); A[2] = fmaf(-BI, XA.w, A[2]);      \
  A[3] = fmaf(BR, XA.w, A[3]); A[3] = fmaf(BI, XA.z, A[3]);       \
  A[4] = fmaf(BR, XB.x, A[4]); A[4] = fmaf(-BI, XB.y, A[4]);      \
  A[5] = fmaf(BR, XB.y, A[5]); A[5] = fmaf(BI, XB.x, A[5]);       \
  A[6] = fmaf(BR, XB.z, A[6]); A[6] = fmaf(-BI, XB.w, A[6]);      \
  A[7] = fmaf(BR, XB.w, A[7]); A[7] = fmaf(BI, XB.z, A[7]);

  if (PACKED) {
    const uint4* pr[4];
#pragma unroll
    for (int r = 0; r < 4; ++r)
      pr[r] = reinterpret_cast<const uint4*>(Bp + (size_t)(row0 + r) * NN + q * 1024);
#pragma unroll
    for (int i4 = 0; i4 < 4; ++i4) {
      const int n0 = q * 1024 + i4 * 256 + lane * 4;   // logical float4 idx
      float4 xa[4], xb[4];
#pragma unroll
      for (int j = 0; j < 4; ++j) {
        int p = n0 + (j ^ xk);           // physical slot of logical column n0+j
        xa[j] = reinterpret_cast<const float4*>(xl)[p];
        xb[j] = reinterpret_cast<const float4*>(xh)[p];
      }
#pragma unroll
      for (int r = 0; r < 4; ++r) {
        uint4 pv = pr[r][i4 * 64 + lane];
        float* a = acc[r];
        uint32_t u;
        u = pv.x; { float br = __uint_as_float(u << 16), bi = __uint_as_float(u & 0xFFFF0000u); CFMA(a, br, bi, xa[0], xb[0]); }
        u = pv.y; { float br = __uint_as_float(u << 16), bi = __uint_as_float(u & 0xFFFF0000u); CFMA(a, br, bi, xa[1], xb[1]); }
        u = pv.z; { float br = __uint_as_float(u << 16), bi = __uint_as_float(u & 0xFFFF0000u); CFMA(a, br, bi, xa[2], xb[2]); }
        u = pv.w; { float br = __uint_as_float(u << 16), bi = __uint_as_float(u & 0xFFFF0000u); CFMA(a, br, bi, xa[3], xb[3]); }
      }
    }
  } else {
    const float4* rr[4];
    const float4* ir[4];
#pragma unroll
    for (int r = 0; r < 4; ++r) {
      rr[r] = reinterpret_cast<const float4*>(Brf + (size_t)(row0 + r) * NN + q * 1024);
      ir[r] = reinterpret_cast<const float4*>(Bif + (size_t)(row0 + r) * NN + q * 1024);
    }
#pragma unroll
    for (int i4 = 0; i4 < 4; ++i4) {
      const int n0 = q * 1024 + i4 * 256 + lane * 4;
      float4 xa[4], xb[4];
#pragma unroll
      for (int j = 0; j < 4; ++j) {
        int p = n0 + (j ^ xk);
        xa[j] = reinterpret_cast<const float4*>(xl)[p];
        xb[j] = reinterpret_cast<const float4*>(xh)[p];
      }
#pragma unroll
      for (int r = 0; r < 4; ++r) {
        float4 pvr = rr[r][i4 * 64 + lane];
        float4 pvi = ir[r][i4 * 64 + lane];
        float* a = acc[r];
        CFMA(a, pvr.x, pvi.x, xa[0], xb[0]);
        CFMA(a, pvr.y, pvi.y, xa[1], xb[1]);
        CFMA(a, pvr.z, pvi.z, xa[2], xb[2]);
        CFMA(a, pvr.w, pvi.w, xa[3], xb[3]);
      }
    }
  }
#undef CFMA

  // ---- hand-unrolled halving butterfly: 32 values -> 32 shfls, named scalars ----
  // Invariant after level with mask M (splitting on lane bit log2(M)): surviving
  // scalar t_i on lane l holds value index (i + high-half offsets per l's bits),
  // reduced over lanes differing in processed bits. Final: lane l holds value
  // j = (l>>1)&31 reduced over bits 5..1; last shfl(1) folds bit 0.
  float t0 = acc[0][0], t1 = acc[0][1], t2 = acc[0][2], t3 = acc[0][3];
  float t4 = acc[0][4], t5 = acc[0][5], t6 = acc[0][6], t7 = acc[0][7];
  float t8 = acc[1][0], t9 = acc[1][1], t10 = acc[1][2], t11 = acc[1][3];
  float t12 = acc[1][4], t13 = acc[1][5], t14 = acc[1][6], t15 = acc[1][7];
  float t16 = acc[2][0], t17 = acc[2][1], t18 = acc[2][2], t19 = acc[2][3];
  float t20 = acc[2][4], t21 = acc[2][5], t22 = acc[2][6], t23 = acc[2][7];
  float t24 = acc[3][0], t25 = acc[3][1], t26 = acc[3][2], t27 = acc[3][3];
  float t28 = acc[3][4], t29 = acc[3][5], t30 = acc[3][6], t31 = acc[3][7];

#define RSTEP(LO, HI, M)                                          \
  { float s_ = up ? LO : HI;                                      \
    s_ = __shfl_xor(s_, M, 64);                                   \
    LO = (up ? HI : LO) + s_; }

  { const bool up = (lane & 32) != 0;
    RSTEP(t0, t16, 32)  RSTEP(t1, t17, 32)  RSTEP(t2, t18, 32)  RSTEP(t3, t19, 32)
    RSTEP(t4, t20, 32)  RSTEP(t5, t21, 32)  RSTEP(t6, t22, 32)  RSTEP(t7, t23, 32)
    RSTEP(t8, t24, 32)  RSTEP(t9, t25, 32)  RSTEP(t10, t26, 32) RSTEP(t11, t27, 32)
    RSTEP(t12, t28, 32) RSTEP(t13, t29, 32) RSTEP(t14, t30, 32) RSTEP(t15, t31, 32)
  }
  { const bool up = (lane & 16) != 0;
    RSTEP(t0, t8, 16)  RSTEP(t1, t9, 16)  RSTEP(t2, t10, 16) RSTEP(t3, t11, 16)
    RSTEP(t4, t12, 16) RSTEP(t5, t13, 16) RSTEP(t6, t14, 16) RSTEP(t7, t15, 16)
  }
  { const bool up = (lane & 8) != 0;
    RSTEP(t0, t4, 8) RSTEP(t1, t5, 8) RSTEP(t2, t6, 8) RSTEP(t3, t7, 8)
  }
  { const bool up = (lane & 4) != 0;
    RSTEP(t0, t2, 4) RSTEP(t1, t3, 4)
  }
  { const bool up = (lane & 2) != 0;
    RSTEP(t0, t1, 2)
  }
#undef RSTEP
  t0 += __shfl_xor(t0, 1, 64);
  if (!(lane & 1)) red[w * 32 + ((lane >> 1) & 31)] = t0;
  __syncthreads();

  // ---- cross-wave sum + diagonal term + writes ----
  if (tid < 128) {
    int rg2 = tid >> 5;
    int v   = tid & 31;
    float s = red[(rg2 * 4 + 0) * 32 + v] + red[(rg2 * 4 + 1) * 32 + v] +
              red[(rg2 * 4 + 2) * 32 + v] + red[(rg2 * 4 + 3) * 32 + v];
    int r  = v >> 3;
    int c  = v & 7;
    int b  = c >> 1;
    int ri = c & 1;
    int m  = blockIdx.x * RPB + rg2 * 4 + r;
    float om = omega[b * NN + m];
    const float* xs = (b < 2) ? xl : xh;
    int mp = m ^ ((m >> 4) & 3);         // swizzled physical slot of node m
    float xr = xs[mp * 4 + (b & 1) * 2];
    float xi = xs[mp * 4 + (b & 1) * 2 + 1];
    // i*omega*(xr + i*xi) = -omega*xi + i*omega*xr
    s += (ri == 0) ? (-om * xi) : (om * xr);
    reinterpret_cast<float*>(stNext)[(b * NN + m) * 2 + ri] = s;
    if (ri == 0) outRe[b * NN + m] = s;  // d_out = REAL part only, [t][b][n]
  }
}

// ---------- host ----------
extern "C" void kernel_launch(void* const* d_in, const int* in_sizes, int n_in,
                              void* d_out, int out_size, void* d_ws, size_t ws_size,
                              hipStream_t stream) {
  const float* B_real = (const float*)d_in[0];
  const float* B_imag = (const float*)d_in[1];
  const float* omega  = (const float*)d_in[2];
  const float* ang    = (const float*)d_in[3];
  float* out = (float*)d_out;

  const int NT = out_size / (BB * NN);                           // 256
  const size_t packBytes = (size_t)NN * NN * sizeof(uint32_t);   // 67 MB
  const size_t stBytes   = (size_t)2 * BB * NN * sizeof(float2); // 256 KB
  const bool packed = ws_size >= packBytes + stBytes;

  uint32_t* Bp;
  float2* st;
  if (packed) {
    Bp = (uint32_t*)d_ws;
    st = (float2*)((char*)d_ws + packBytes);
  } else {
    Bp = nullptr;
    st = (float2*)d_ws;                                          // needs 256 KB
  }
  float2* st0 = st;
  float2* st1 = st + BB * NN;

  const size_t shmem = (size_t)(NN * 8 + 16 * 32) * sizeof(float);  // 133120 B
  (void)hipFuncSetAttribute((const void*)&step_kernel<true>,
                            hipFuncAttributeMaxDynamicSharedMemorySize, (int)shmem);
  (void)hipFuncSetAttribute((const void*)&step_kernel<false>,
                            hipFuncAttributeMaxDynamicSharedMemorySize, (int)shmem);

  if (packed) {
    pack_kernel<<<NN * NN / 4 / 256, 256, 0, stream>>>(B_real, B_imag, Bp);
  }
  init_kernel<<<(BB * NN + 255) / 256, 256, 0, stream>>>(ang, st0, out);

  for (int t = 1; t < NT; ++t) {
    float2* sp = ((t - 1) & 1) ? st1 : st0;
    float2* sn = (t & 1) ? st1 : st0;
    float* outT = out + (size_t)t * BB * NN;
    if (packed) {
      step_kernel<true><<<NN / RPB, TPB, shmem, stream>>>(
          Bp, nullptr, nullptr, omega, sp, sn, outT);
    } else {
      step_kernel<false><<<NN / RPB, TPB, shmem, stream>>>(
          nullptr, B_real, B_imag, omega, sp, sn, outT);
    }
  }
}

// Round 9
// 3873.847 us; speedup vs baseline: 2.6485x; 1.0175x over previous
//
#include <hip/hip_runtime.h>
#include <stdint.h>

#define NN 4096
#define BB 4
#define RPB 16          // rows per block
#define TPB 1024

// ---------- bf16 round-to-nearest-even ----------
__device__ __forceinline__ uint32_t bf16rne(float f) {
  uint32_t u = __float_as_uint(f);
  return (u + 0x7FFFu + ((u >> 16) & 1u)) >> 16;
}

// ---------- straight pack: Bp[row*NN+c] = bf16(Br)|bf16(Bi)<<16 ----------
__global__ void pack_kernel(const float* __restrict__ Br, const float* __restrict__ Bi,
                            uint32_t* __restrict__ Bp) {
  int i = blockIdx.x * blockDim.x + threadIdx.x;   // over N*N/4
  float4 r = reinterpret_cast<const float4*>(Br)[i];
  float4 m = reinterpret_cast<const float4*>(Bi)[i];
  uint4 o;
  o.x = bf16rne(r.x) | (bf16rne(m.x) << 16);
  o.y = bf16rne(r.y) | (bf16rne(m.y) << 16);
  o.z = bf16rne(r.z) | (bf16rne(m.z) << 16);
  o.w = bf16rne(r.w) | (bf16rne(m.w) << 16);
  reinterpret_cast<uint4*>(Bp)[i] = o;
}

// ---------- x0 = exp(i*theta): state (complex interleaved) + out real plane t=0 ----------
__global__ void init_kernel(const float* __restrict__ ang,
                            float2* __restrict__ st0, float* __restrict__ out0) {
  int i = blockIdx.x * blockDim.x + threadIdx.x;
  if (i < BB * NN) {
    float s, c;
    sincosf(ang[i], &s, &c);
    st0[i] = make_float2(c, s);
    out0[i] = c;
  }
}

// ---------- one recurrence step ----------
// state [b][n] complex interleaved (float2); d_out gets REAL part only, [t][b][n]
// LDS x: logical float4 n={r0,i0,r1,i1} at physical p(n)=n^((n>>4)&3).
template <bool PACKED>
__global__ __launch_bounds__(TPB)
void step_kernel(const uint32_t* __restrict__ Bp,
                 const float* __restrict__ Brf,
                 const float* __restrict__ Bif,
                 const float* __restrict__ omega,
                 const float2* __restrict__ stPrev,
                 float2* __restrict__ stNext,
                 float* __restrict__ outRe) {
  extern __shared__ float lds[];
  float* xl  = lds;                // 4096 float4 = 64 KB (batches 0,1)
  float* xh  = lds + NN * 4;       // 64 KB (batches 2,3)
  float* red = lds + NN * 8;       // 2 KB

  const int tid = threadIdx.x;

  // ---- stage x_t into LDS: one swizzled b128 write per thread-iter ----
#pragma unroll
  for (int k = 0; k < 8; ++k) {
    int idx  = tid + k * TPB;            // 0..8191
    int half = idx >> 12;                // 0 -> xl, 1 -> xh
    int n    = idx & (NN - 1);
    float2 v0 = stPrev[(half * 2    ) * NN + n];
    float2 v1 = stPrev[(half * 2 + 1) * NN + n];
    float4 w4 = make_float4(v0.x, v0.y, v1.x, v1.y);
    int p = n ^ ((n >> 4) & 3);          // swizzled physical slot
    reinterpret_cast<float4*>(half ? xh : xl)[p] = w4;
  }
  __syncthreads();

  const int w    = tid >> 6;
  const int lane = tid & 63;
  const int rg   = w >> 2;             // row group (4 rows)
  const int q    = w & 3;              // n-quarter
  const int row0 = blockIdx.x * RPB + rg * 4;
  const int xk   = (lane >> 2) & 3;    // swizzle key for this lane's 4-float4 window

  float acc[4][8];
#pragma unroll
  for (int r = 0; r < 4; ++r)
#pragma unroll
    for (int c = 0; c < 8; ++c) acc[r][c] = 0.0f;

#define CFMA(A, BR, BI, XA, XB)                                   \
  A[0] = fmaf(BR, XA.x, A[0]); A[0] = fmaf(-BI, XA.y, A[0]);      \
  A[1] = fmaf(BR, XA.y, A[1]); A[1] = fmaf(BI, XA.x, A[1]);       \
  A[2] = fmaf(BR, XA.z, A[2]); A[2] = fmaf(-BI, XA.w, A[2]);      \
  A[3] = fmaf(BR, XA.w, A[3]); A[3] = fmaf(BI, XA.z, A[3]);       \
  A[4] = fmaf(BR, XB.x, A[4]); A[4] = fmaf(-BI, XB.y, A[4]);      \
  A[5] = fmaf(BR, XB.y, A[5]); A[5] = fmaf(BI, XB.x, A[5]);       \
  A[6] = fmaf(BR, XB.z, A[6]); A[6] = fmaf(-BI, XB.w, A[6]);      \
  A[7] = fmaf(BR, XB.w, A[7]); A[7] = fmaf(BI, XB.z, A[7]);

// one B element (packed bf16 pair) against x-columns XA/XB into acc row RLIT
#define CUNPK(PVCOMP, RLIT, XA, XB)                                             \
  { uint32_t u = PVCOMP;                                                        \
    float br = __uint_as_float(u << 16);                                        \
    float bi = __uint_as_float(u & 0xFFFF0000u);                                \
    float* a = acc[RLIT];                                                       \
    CFMA(a, br, bi, XA, XB); }

// full row RLIT for one i4-iter, using prefetched uint4 PV
#define CROWP(RLIT, PV)                                                         \
  CUNPK(PV.x, RLIT, xa[0], xb[0])                                               \
  CUNPK(PV.y, RLIT, xa[1], xb[1])                                               \
  CUNPK(PV.z, RLIT, xa[2], xb[2])                                               \
  CUNPK(PV.w, RLIT, xa[3], xb[3])

// one pipelined iteration: issue next-iter B loads first (longest latency),
// then ds-read this iter's x window, then FMA with current (already-resident) B.
#define PITER(I4, C0, C1, C2, C3, N0, N1, N2, N3, DOLOAD)                       \
  {                                                                             \
    if (DOLOAD) {                                                               \
      N0 = pr[0][(I4 + 1) * 64 + lane];                                         \
      N1 = pr[1][(I4 + 1) * 64 + lane];                                         \
      N2 = pr[2][(I4 + 1) * 64 + lane];                                         \
      N3 = pr[3][(I4 + 1) * 64 + lane];                                         \
    }                                                                           \
    const int n0 = q * 1024 + I4 * 256 + lane * 4;                              \
    float4 xa[4], xb[4];                                                        \
    _Pragma("unroll")                                                           \
    for (int j = 0; j < 4; ++j) {                                               \
      int p = n0 + (j ^ xk);                                                    \
      xa[j] = reinterpret_cast<const float4*>(xl)[p];                           \
      xb[j] = reinterpret_cast<const float4*>(xh)[p];                           \
    }                                                                           \
    CROWP(0, C0) CROWP(1, C1) CROWP(2, C2) CROWP(3, C3)                         \
  }

  if (PACKED) {
    const uint4* pr[4];
#pragma unroll
    for (int r = 0; r < 4; ++r)
      pr[r] = reinterpret_cast<const uint4*>(Bp + (size_t)(row0 + r) * NN + q * 1024);
    // prologue: load iter-0 B into the A buffer
    uint4 pvA0 = pr[0][lane], pvA1 = pr[1][lane], pvA2 = pr[2][lane], pvA3 = pr[3][lane];
    uint4 pvB0, pvB1, pvB2, pvB3;
    PITER(0, pvA0, pvA1, pvA2, pvA3, pvB0, pvB1, pvB2, pvB3, 1)
    PITER(1, pvB0, pvB1, pvB2, pvB3, pvA0, pvA1, pvA2, pvA3, 1)
    PITER(2, pvA0, pvA1, pvA2, pvA3, pvB0, pvB1, pvB2, pvB3, 1)
    PITER(3, pvB0, pvB1, pvB2, pvB3, pvA0, pvA1, pvA2, pvA3, 0)
  } else {
    const float4* rr[4];
    const float4* ir[4];
#pragma unroll
    for (int r = 0; r < 4; ++r) {
      rr[r] = reinterpret_cast<const float4*>(Brf + (size_t)(row0 + r) * NN + q * 1024);
      ir[r] = reinterpret_cast<const float4*>(Bif + (size_t)(row0 + r) * NN + q * 1024);
    }
#pragma unroll
    for (int i4 = 0; i4 < 4; ++i4) {
      const int n0 = q * 1024 + i4 * 256 + lane * 4;
      float4 xa[4], xb[4];
#pragma unroll
      for (int j = 0; j < 4; ++j) {
        int p = n0 + (j ^ xk);
        xa[j] = reinterpret_cast<const float4*>(xl)[p];
        xb[j] = reinterpret_cast<const float4*>(xh)[p];
      }
#pragma unroll
      for (int r = 0; r < 4; ++r) {
        float4 pvr = rr[r][i4 * 64 + lane];
        float4 pvi = ir[r][i4 * 64 + lane];
        float* a = acc[r];
        CFMA(a, pvr.x, pvi.x, xa[0], xb[0]);
        CFMA(a, pvr.y, pvi.y, xa[1], xb[1]);
        CFMA(a, pvr.z, pvi.z, xa[2], xb[2]);
        CFMA(a, pvr.w, pvi.w, xa[3], xb[3]);
      }
    }
  }
#undef PITER
#undef CROWP
#undef CUNPK
#undef CFMA

  // ---- hand-unrolled halving butterfly: 32 values -> 32 shfls, named scalars ----
  float t0 = acc[0][0], t1 = acc[0][1], t2 = acc[0][2], t3 = acc[0][3];
  float t4 = acc[0][4], t5 = acc[0][5], t6 = acc[0][6], t7 = acc[0][7];
  float t8 = acc[1][0], t9 = acc[1][1], t10 = acc[1][2], t11 = acc[1][3];
  float t12 = acc[1][4], t13 = acc[1][5], t14 = acc[1][6], t15 = acc[1][7];
  float t16 = acc[2][0], t17 = acc[2][1], t18 = acc[2][2], t19 = acc[2][3];
  float t20 = acc[2][4], t21 = acc[2][5], t22 = acc[2][6], t23 = acc[2][7];
  float t24 = acc[3][0], t25 = acc[3][1], t26 = acc[3][2], t27 = acc[3][3];
  float t28 = acc[3][4], t29 = acc[3][5], t30 = acc[3][6], t31 = acc[3][7];

#define RSTEP(LO, HI, M)                                          \
  { float s_ = up ? LO : HI;                                      \
    s_ = __shfl_xor(s_, M, 64);                                   \
    LO = (up ? HI : LO) + s_; }

  { const bool up = (lane & 32) != 0;
    RSTEP(t0, t16, 32)  RSTEP(t1, t17, 32)  RSTEP(t2, t18, 32)  RSTEP(t3, t19, 32)
    RSTEP(t4, t20, 32)  RSTEP(t5, t21, 32)  RSTEP(t6, t22, 32)  RSTEP(t7, t23, 32)
    RSTEP(t8, t24, 32)  RSTEP(t9, t25, 32)  RSTEP(t10, t26, 32) RSTEP(t11, t27, 32)
    RSTEP(t12, t28, 32) RSTEP(t13, t29, 32) RSTEP(t14, t30, 32) RSTEP(t15, t31, 32)
  }
  { const bool up = (lane & 16) != 0;
    RSTEP(t0, t8, 16)  RSTEP(t1, t9, 16)  RSTEP(t2, t10, 16) RSTEP(t3, t11, 16)
    RSTEP(t4, t12, 16) RSTEP(t5, t13, 16) RSTEP(t6, t14, 16) RSTEP(t7, t15, 16)
  }
  { const bool up = (lane & 8) != 0;
    RSTEP(t0, t4, 8) RSTEP(t1, t5, 8) RSTEP(t2, t6, 8) RSTEP(t3, t7, 8)
  }
  { const bool up = (lane & 4) != 0;
    RSTEP(t0, t2, 4) RSTEP(t1, t3, 4)
  }
  { const bool up = (lane & 2) != 0;
    RSTEP(t0, t1, 2)
  }
#undef RSTEP
  t0 += __shfl_xor(t0, 1, 64);
  if (!(lane & 1)) red[w * 32 + ((lane >> 1) & 31)] = t0;
  __syncthreads();

  // ---- cross-wave sum + diagonal term + writes ----
  if (tid < 128) {
    int rg2 = tid >> 5;
    int v   = tid & 31;
    float s = red[(rg2 * 4 + 0) * 32 + v] + red[(rg2 * 4 + 1) * 32 + v] +
              red[(rg2 * 4 + 2) * 32 + v] + red[(rg2 * 4 + 3) * 32 + v];
    int r  = v >> 3;
    int c  = v & 7;
    int b  = c >> 1;
    int ri = c & 1;
    int m  = blockIdx.x * RPB + rg2 * 4 + r;
    float om = omega[b * NN + m];
    const float* xs = (b < 2) ? xl : xh;
    int mp = m ^ ((m >> 4) & 3);         // swizzled physical slot of node m
    float xr = xs[mp * 4 + (b & 1) * 2];
    float xi = xs[mp * 4 + (b & 1) * 2 + 1];
    // i*omega*(xr + i*xi) = -omega*xi + i*omega*xr
    s += (ri == 0) ? (-om * xi) : (om * xr);
    reinterpret_cast<float*>(stNext)[(b * NN + m) * 2 + ri] = s;
    if (ri == 0) outRe[b * NN + m] = s;  // d_out = REAL part only, [t][b][n]
  }
}

// ---------- host ----------
extern "C" void kernel_launch(void* const* d_in, const int* in_sizes, int n_in,
                              void* d_out, int out_size, void* d_ws, size_t ws_size,
                              hipStream_t stream) {
  const float* B_real = (const float*)d_in[0];
  const float* B_imag = (const float*)d_in[1];
  const float* omega  = (const float*)d_in[2];
  const float* ang    = (const float*)d_in[3];
  float* out = (float*)d_out;

  const int NT = out_size / (BB * NN);                           // 256
  const size_t packBytes = (size_t)NN * NN * sizeof(uint32_t);   // 67 MB
  const size_t stBytes   = (size_t)2 * BB * NN * sizeof(float2); // 256 KB
  const bool packed = ws_size >= packBytes + stBytes;

  uint32_t* Bp;
  float2* st;
  if (packed) {
    Bp = (uint32_t*)d_ws;
    st = (float2*)((char*)d_ws + packBytes);
  } else {
    Bp = nullptr;
    st = (float2*)d_ws;                                          // needs 256 KB
  }
  float2* st0 = st;
  float2* st1 = st + BB * NN;

  const size_t shmem = (size_t)(NN * 8 + 16 * 32) * sizeof(float);  // 133120 B
  (void)hipFuncSetAttribute((const void*)&step_kernel<true>,
                            hipFuncAttributeMaxDynamicSharedMemorySize, (int)shmem);
  (void)hipFuncSetAttribute((const void*)&step_kernel<false>,
                            hipFuncAttributeMaxDynamicSharedMemorySize, (int)shmem);

  if (packed) {
    pack_kernel<<<NN * NN / 4 / 256, 256, 0, stream>>>(B_real, B_imag, Bp);
  }
  init_kernel<<<(BB * NN + 255) / 256, 256, 0, stream>>>(ang, st0, out);

  for (int t = 1; t < NT; ++t) {
    float2* sp = ((t - 1) & 1) ? st1 : st0;
    float2* sn = (t & 1) ? st1 : st0;
    float* outT = out + (size_t)t * BB * NN;
    if (packed) {
      step_kernel<true><<<NN / RPB, TPB, shmem, stream>>>(
          Bp, nullptr, nullptr, omega, sp, sn, outT);
    } else {
      step_kernel<false><<<NN / RPB, TPB, shmem, stream>>>(
          nullptr, B_real, B_imag, omega, sp, sn, outT);
    }
  }
}